// Round 8
// baseline (1681.027 us; speedup 1.0000x reference)
//
#include <hip/hip_runtime.h>
#include <hip/hip_bf16.h>
#include <stdint.h>

typedef unsigned short u16;
typedef __attribute__((ext_vector_type(8))) __bf16 bf16x8;
typedef __attribute__((ext_vector_type(16))) float f32x16;

#define BATCH 8192
#define HID   2048
#define COMB  4096
#define NTT   128   // K tiles of 32
#define KB16  256   // COMB/16

__device__ __forceinline__ u16 f2bf(float f) {
  uint32_t u = __float_as_uint(f);
  u += 0x7fffu + ((u >> 16) & 1u);
  return (u16)(u >> 16);
}
__device__ __forceinline__ float bf2f(u16 b) {
  return __uint_as_float(((uint32_t)b) << 16);
}
__device__ __forceinline__ float fsigmoid(float x) { return 1.0f / (1.0f + __expf(-x)); }
__device__ __forceinline__ float ftanh(float x) { return 1.0f - 2.0f / (__expf(2.0f * x) + 1.0f); }

__device__ __forceinline__ void gload_lds16(const void* g, void* l) {
  __builtin_amdgcn_global_load_lds(
      (__attribute__((address_space(1))) void*)(uintptr_t)g,
      (__attribute__((address_space(3))) void*)(uintptr_t)l,
      16, 0, 0);
}

#define BARRIER() do { asm volatile("" ::: "memory"); __builtin_amdgcn_s_barrier(); asm volatile("" ::: "memory"); } while (0)
#define VM4() asm volatile("s_waitcnt vmcnt(4)" ::: "memory")
#define VM0() asm volatile("s_waitcnt vmcnt(0)" ::: "memory")

// MFMA with accumulator FORCED into AGPRs (frees arch VGPRs; no spill at 128x128 wave tile)
#define MFMA32(ACC, AV, BV) \
  asm("v_mfma_f32_32x32x16_bf16 %0, %1, %2, %0" : "+a"(ACC) : "v"(AV), "v"(BV))

// ---- pack [x | h_prev] f32 -> A1 bf16 [8192][4096] ----
__global__ void pack_A_kernel(const float* __restrict__ x, const float* __restrict__ h,
                              u16* __restrict__ A1) {
  const size_t tid = (size_t)blockIdx.x * blockDim.x + threadIdx.x;
  const int r  = (int)(tid >> 9);
  const int c8 = (int)(tid & 511);
  const float* s = (c8 < 256) ? (x + (size_t)r * 2048 + (size_t)c8 * 8)
                              : (h + (size_t)r * 2048 + (size_t)(c8 - 256) * 8);
  const float4 v0 = ((const float4*)s)[0];
  const float4 v1 = ((const float4*)s)[1];
  const uint32_t p0 = (uint32_t)f2bf(v0.x) | ((uint32_t)f2bf(v0.y) << 16);
  const uint32_t p1 = (uint32_t)f2bf(v0.z) | ((uint32_t)f2bf(v0.w) << 16);
  const uint32_t p2 = (uint32_t)f2bf(v1.x) | ((uint32_t)f2bf(v1.y) << 16);
  const uint32_t p3 = (uint32_t)f2bf(v1.z) | ((uint32_t)f2bf(v1.w) << 16);
  *(uint4*)(A1 + tid * 8) = make_uint4(p0, p1, p2, p3);
}

// ---- pack W [4096 k][2048 n] f32 -> fragment-linear Bp[nb][kk][lane][8] bf16 ----
// chunk(nb,kk): lane l holds B[col=nb*32+(l&31)][k=kk*16+(l>>5)*8 .. +8)
__global__ void packW_kernel(const float* __restrict__ src, u16* __restrict__ dst) {
  __shared__ float tile[32][33];
  const int n0 = blockIdx.x * 32;
  const int k0 = blockIdx.y * 32;
  const int tx = threadIdx.x, ty = threadIdx.y;  // 32 x 8
#pragma unroll
  for (int i = 0; i < 32; i += 8)
    tile[ty + i][tx] = src[(size_t)(k0 + ty + i) * 2048 + n0 + tx];
  __syncthreads();
  const int tid = ty * 32 + tx;
  if (tid < 128) {
    const int h = tid >> 6, l = tid & 63;
    const int cl = l & 31, kh = l >> 5;
    const int kl = h * 16 + kh * 8;
    uint32_t p[4];
#pragma unroll
    for (int e = 0; e < 4; ++e) {
      const u16 lo = f2bf(tile[kl + 2 * e][cl]);
      const u16 hi = f2bf(tile[kl + 2 * e + 1][cl]);
      p[e] = (uint32_t)lo | ((uint32_t)hi << 16);
    }
    const size_t off = (((size_t)(n0 >> 5) * KB16 + (k0 >> 4) + h) * 64 + l) * 8;
    *(uint4*)(dst + off) = make_uint4(p[0], p[1], p[2], p[3]);
  }
}

// ---- 256x256x32 GEMM: 4 waves, wave-tile 128x128, acc in AGPR, B direct from L2 ----
// LDS 48KB: A slots 16KB @0,16K,32K (triple buffer)
template <int MODE>
__global__ __launch_bounds__(256, 1) void gemmfl_kernel(
    const u16* __restrict__ A1, const u16* __restrict__ RH,
    const u16* __restrict__ Bp, const float* __restrict__ h_prev,
    const float* __restrict__ bias0, const float* __restrict__ bias1,
    u16* __restrict__ Z, u16* __restrict__ RHout, float* __restrict__ out) {
  extern __shared__ char smem[];
  constexpr int NBN = (MODE == 0) ? 16 : 8;

  const int t = threadIdx.x;
  const int l = t & 63, w = t >> 6;        // 4 waves
  const int wm = w >> 1, wn = w & 1;       // 2M x 2N; wave tile 128x128
  const int l31 = l & 31;
  const int kb  = l >> 5;

  const int nwg = 32 * NBN;
  int bid = blockIdx.x;
  bid = (bid & 7) * (nwg >> 3) + (bid >> 3);
  const int bm = bid / NBN, bn = bid % NBN;
  const int arow = bm * 256;

  // A staging (R5-verified): lane l -> row srow=l>>2, granule sg; LDS dest linear
  const int srow = l >> 2;
  const int sg   = (l & 3) ^ ((srow >> 1) & 3);

  auto stageA = [&](int T, char* slot) {
    const u16* src;
    size_t ld;
    int koff;
    if constexpr (MODE == 1) {
      if (T >= 64) { src = RH; ld = HID;  koff = T * 32 - 2048; }
      else         { src = A1; ld = COMB; koff = T * 32; }
    } else {
      src = A1; ld = COMB; koff = T * 32;
    }
#pragma unroll
    for (int i = 0; i < 4; ++i) {
      const int r0 = w * 64 + i * 16;
      gload_lds16(src + (size_t)(arow + r0 + srow) * ld + koff + sg * 8, slot + r0 * 64);
    }
  };

  // B fragment base: per-thread, fragment-linear
  const int nb0 = bn * 8 + wn * 4;
  const u16* Bbase = Bp + ((size_t)nb0 * KB16 * 64 + l) * 8;
  auto loadB = [&](int T, bf16x8 (&bb)[4][2]) {
#pragma unroll
    for (int nt = 0; nt < 4; ++nt)
#pragma unroll
      for (int ks = 0; ks < 2; ++ks)
        bb[nt][ks] = *(const bf16x8*)(Bbase + (((size_t)nt * KB16 + T * 2 + ks) * 64) * 8);
  };

  // lane-constant swizzled A read offsets (rows 32t + l31)
  const int loff0 = l31 * 64 + (((0 + kb) ^ ((l31 >> 1) & 3)) << 4);
  const int loff1 = l31 * 64 + (((2 + kb) ^ ((l31 >> 1) & 3)) << 4);

  char* As0 = smem;
  char* As1 = smem + 16384;
  char* As2 = smem + 32768;

  f32x16 acc[4][4] = {};
  bf16x8 bbA[4][2], bbB[4][2];

  // Prologue
  stageA(0, As0); stageA(1, As1);
  loadB(0, bbA);
  VM0();
  BARRIER();

#define STEP(J, BBCUR, BBNXT)                                                   \
  {                                                                             \
    if ((J) < NTT - 1) loadB((J) + 1, BBNXT);                                   \
    if ((J) < NTT - 2) stageA((J) + 2, As2);                                    \
    bf16x8 af[4][2];                                                            \
    _Pragma("unroll") for (int mt = 0; mt < 4; ++mt) {                          \
      const char* p = As0 + (wm * 128 + mt * 32) * 64;                          \
      af[mt][0] = *(const bf16x8*)(p + loff0);                                  \
      af[mt][1] = *(const bf16x8*)(p + loff1);                                  \
    }                                                                           \
    _Pragma("unroll") for (int mt = 0; mt < 4; ++mt)                            \
      _Pragma("unroll") for (int nt = 0; nt < 4; ++nt) {                        \
        MFMA32(acc[mt][nt], af[mt][0], BBCUR[nt][0]);                           \
        MFMA32(acc[mt][nt], af[mt][1], BBCUR[nt][1]);                           \
      }                                                                         \
    if ((J) < NTT - 2) { VM4(); } else { VM0(); }                               \
    if ((J) < NTT - 1) BARRIER();                                               \
    char* ta_ = As0; As0 = As1; As1 = As2; As2 = ta_;                           \
  }

  for (int j = 0; j < NTT; j += 2) {
    STEP(j, bbA, bbB);
    STEP(j + 1, bbB, bbA);
  }
#undef STEP

  // MFMA->accvgpr_read hazard insurance
  asm volatile("s_nop 7\n\ts_nop 7\n\ts_nop 7" ::: );

  // ---- epilogue: row = arow + wm*128 + mt*32 + (e&3)+8*(e>>2)+4*kb ; col = bn*256 + wn*128 + nt*32 + l31
  const int r0g = arow + wm * 128 + kb * 4;
  const int c0g = bn * 256 + wn * 128 + l31;
  if constexpr (MODE == 0) {
    const bool isZ = (bn < 8);
    const float* bias = isZ ? bias0 : bias1;
#pragma unroll
    for (int nt = 0; nt < 4; ++nt) {
      const int colg = c0g + nt * 32;
      const int col = isZ ? colg : (colg - 2048);
      const float bv = bias[col];
#pragma unroll
      for (int mt = 0; mt < 4; ++mt)
#pragma unroll
        for (int e = 0; e < 16; ++e) {
          const int row = r0g + mt * 32 + (e & 3) + 8 * (e >> 2);
          const size_t idx = (size_t)row * HID + col;
          const float v = acc[mt][nt][e] + bv;
          if (isZ) {
            Z[idx] = f2bf(fsigmoid(v));
          } else {
            const float rv = fsigmoid(v);
            RHout[idx] = f2bf(rv * h_prev[idx]);
          }
        }
    }
  } else {
#pragma unroll
    for (int nt = 0; nt < 4; ++nt) {
      const int col = c0g + nt * 32;
      const float bv = bias0[col];
#pragma unroll
      for (int mt = 0; mt < 4; ++mt)
#pragma unroll
        for (int e = 0; e < 16; ++e) {
          const int row = r0g + mt * 32 + (e & 3) + 8 * (e >> 2);
          const size_t idx = (size_t)row * HID + col;
          const float nn = ftanh(acc[mt][nt][e] + bv);
          const float zz = bf2f(Z[idx]);
          const float hp = h_prev[idx];
          out[idx] = (1.0f - zz) * hp + zz * nn;
        }
    }
  }
}

extern "C" void kernel_launch(void* const* d_in, const int* in_sizes, int n_in,
                              void* d_out, int out_size, void* d_ws, size_t ws_size,
                              hipStream_t stream) {
  const float* x  = (const float*)d_in[0];
  const float* h  = (const float*)d_in[1];
  const float* Wz = (const float*)d_in[2];
  const float* bz = (const float*)d_in[3];
  const float* Wr = (const float*)d_in[4];
  const float* br = (const float*)d_in[5];
  const float* Wn = (const float*)d_in[6];
  const float* bn = (const float*)d_in[7];
  float* out = (float*)d_out;

  char* ws = (char*)d_ws;
  u16* A1  = (u16*)(ws);                    // 8192*4096*2 = 67108864
  u16* RH  = (u16*)(ws + 67108864);         // 8192*2048*2 = 33554432
  u16* Bp1 = (u16*)(ws + 100663296);        // 4096*4096*2 = 33554432  (frag-packed [Wz‖Wr])
  u16* Bp2 = (u16*)(ws + 134217728);        // 2048*4096*2 = 16777216  (frag-packed Wn)
  u16* Z   = (u16*)(ws + 150994944);        // 8192*2048*2 = 33554432

  (void)hipFuncSetAttribute(reinterpret_cast<const void*>(&gemmfl_kernel<0>),
                            hipFuncAttributeMaxDynamicSharedMemorySize, 49152);
  (void)hipFuncSetAttribute(reinterpret_cast<const void*>(&gemmfl_kernel<1>),
                            hipFuncAttributeMaxDynamicSharedMemorySize, 49152);

  pack_A_kernel<<<16384, 256, 0, stream>>>(x, h, A1);
  dim3 tb(32, 8);
  packW_kernel<<<dim3(64, 128), tb, 0, stream>>>(Wz, Bp1);
  packW_kernel<<<dim3(64, 128), tb, 0, stream>>>(Wr, Bp1 + (size_t)2048 * 4096);
  packW_kernel<<<dim3(64, 128), tb, 0, stream>>>(Wn, Bp2);

  gemmfl_kernel<0><<<dim3(512), 256, 49152, stream>>>(A1, nullptr, Bp1, h, bz, br, Z, RH, nullptr);
  gemmfl_kernel<1><<<dim3(256), 256, 49152, stream>>>(A1, RH, Bp2, h, bn, nullptr, Z, nullptr, out);
}

// Round 9
// 734.655 us; speedup vs baseline: 2.2882x; 2.2882x over previous
//
#include <hip/hip_runtime.h>
#include <hip/hip_bf16.h>
#include <stdint.h>

typedef unsigned short u16;
typedef __attribute__((ext_vector_type(8))) __bf16 bf16x8;
typedef __attribute__((ext_vector_type(16))) float f32x16;

#define BATCH 8192
#define HID   2048
#define COMB  4096
#define NTT   128   // K tiles of 32
#define KB16  256   // COMB/16

__device__ __forceinline__ u16 f2bf(float f) {
  uint32_t u = __float_as_uint(f);
  u += 0x7fffu + ((u >> 16) & 1u);
  return (u16)(u >> 16);
}
__device__ __forceinline__ float bf2f(u16 b) {
  return __uint_as_float(((uint32_t)b) << 16);
}
__device__ __forceinline__ float fsigmoid(float x) { return 1.0f / (1.0f + __expf(-x)); }
__device__ __forceinline__ float ftanh(float x) { return 1.0f - 2.0f / (__expf(2.0f * x) + 1.0f); }

__device__ __forceinline__ void gload_lds16(const void* g, void* l) {
  __builtin_amdgcn_global_load_lds(
      (__attribute__((address_space(1))) void*)(uintptr_t)g,
      (__attribute__((address_space(3))) void*)(uintptr_t)l,
      16, 0, 0);
}

#define BARRIER() do { asm volatile("" ::: "memory"); __builtin_amdgcn_s_barrier(); asm volatile("" ::: "memory"); } while (0)
#define VM2() asm volatile("s_waitcnt vmcnt(2)" ::: "memory")
#define VM0() asm volatile("s_waitcnt vmcnt(0)" ::: "memory")

// ---- pack [x | h_prev] f32 -> A1 bf16 [8192][4096] ----
__global__ void pack_A_kernel(const float* __restrict__ x, const float* __restrict__ h,
                              u16* __restrict__ A1) {
  const size_t tid = (size_t)blockIdx.x * blockDim.x + threadIdx.x;
  const int r  = (int)(tid >> 9);
  const int c8 = (int)(tid & 511);
  const float* s = (c8 < 256) ? (x + (size_t)r * 2048 + (size_t)c8 * 8)
                              : (h + (size_t)r * 2048 + (size_t)(c8 - 256) * 8);
  const float4 v0 = ((const float4*)s)[0];
  const float4 v1 = ((const float4*)s)[1];
  const uint32_t p0 = (uint32_t)f2bf(v0.x) | ((uint32_t)f2bf(v0.y) << 16);
  const uint32_t p1 = (uint32_t)f2bf(v0.z) | ((uint32_t)f2bf(v0.w) << 16);
  const uint32_t p2 = (uint32_t)f2bf(v1.x) | ((uint32_t)f2bf(v1.y) << 16);
  const uint32_t p3 = (uint32_t)f2bf(v1.z) | ((uint32_t)f2bf(v1.w) << 16);
  *(uint4*)(A1 + tid * 8) = make_uint4(p0, p1, p2, p3);
}

// ---- pack W [4096 k][2048 n] f32 -> fragment-linear Bp[nb][kk][lane][8] bf16 ----
// chunk(nb,kk): lane l holds B[col=nb*32+(l&31)][k=kk*16+(l>>5)*8 .. +8)   [R8-verified]
__global__ void packW_kernel(const float* __restrict__ src, u16* __restrict__ dst) {
  __shared__ float tile[32][33];
  const int n0 = blockIdx.x * 32;
  const int k0 = blockIdx.y * 32;
  const int tx = threadIdx.x, ty = threadIdx.y;  // 32 x 8
#pragma unroll
  for (int i = 0; i < 32; i += 8)
    tile[ty + i][tx] = src[(size_t)(k0 + ty + i) * 2048 + n0 + tx];
  __syncthreads();
  const int tid = ty * 32 + tx;
  if (tid < 128) {
    const int h = tid >> 6, l = tid & 63;
    const int cl = l & 31, kh = l >> 5;
    const int kl = h * 16 + kh * 8;
    uint32_t p[4];
#pragma unroll
    for (int e = 0; e < 4; ++e) {
      const u16 lo = f2bf(tile[kl + 2 * e][cl]);
      const u16 hi = f2bf(tile[kl + 2 * e + 1][cl]);
      p[e] = (uint32_t)lo | ((uint32_t)hi << 16);
    }
    const size_t off = (((size_t)(n0 >> 5) * KB16 + (k0 >> 4) + h) * 64 + l) * 8;
    *(uint4*)(dst + off) = make_uint4(p[0], p[1], p[2], p[3]);
  }
}

// ---- 256x256x32 GEMM: 8 waves, wave-tile 128x64, A in LDS (triple), B in registers ----
// LDS 48KB: A slots 16KB @0,16K,32K
template <int MODE>
__global__ __launch_bounds__(512, 2) void gemmbr_kernel(
    const u16* __restrict__ A1, const u16* __restrict__ RH,
    const u16* __restrict__ Bp, const float* __restrict__ h_prev,
    const float* __restrict__ bias0, const float* __restrict__ bias1,
    u16* __restrict__ Z, u16* __restrict__ RHout, float* __restrict__ out) {
  extern __shared__ char smem[];
  constexpr int NBN = (MODE == 0) ? 16 : 8;

  const int t = threadIdx.x;
  const int l = t & 63, w = t >> 6;        // 8 waves
  const int wm = w >> 2, wn = w & 3;       // 2M x 4N; wave tile 128x64
  const int l31 = l & 31;
  const int kb  = l >> 5;

  const int nwg = 32 * NBN;
  int bid = blockIdx.x;
  bid = (bid & 7) * (nwg >> 3) + (bid >> 3);
  const int bm = bid / NBN, bn = bid % NBN;
  const int arow = bm * 256;

  // A staging (R5-verified swizzle for 64B rows): lane -> row l>>2, granule (l&3)^((row>>1)&3)
  const int srow = l >> 2;
  const int sg   = (l & 3) ^ ((srow >> 1) & 3);

  auto stageA = [&](int T, char* slot) {
    const u16* src;
    size_t ld;
    int koff;
    if constexpr (MODE == 1) {
      if (T >= 64) { src = RH; ld = HID;  koff = T * 32 - 2048; }
      else         { src = A1; ld = COMB; koff = T * 32; }
    } else {
      src = A1; ld = COMB; koff = T * 32;
    }
#pragma unroll
    for (int i = 0; i < 2; ++i) {
      const int r0 = w * 32 + i * 16;
      gload_lds16(src + (size_t)(arow + r0 + srow) * ld + koff + sg * 8, slot + r0 * 64);
    }
  };

  // B fragment streams (fragment-linear layout). 4 chunks: (nt,ks); advance 1024 u16/tile.
  const int nb0 = bn * 8 + wn * 2;
  const u16* p00 = Bp + (((size_t)(nb0 + 0) * KB16 + 0) * 64 + l) * 8;
  const u16* p01 = Bp + (((size_t)(nb0 + 0) * KB16 + 1) * 64 + l) * 8;
  const u16* p10 = Bp + (((size_t)(nb0 + 1) * KB16 + 0) * 64 + l) * 8;
  const u16* p11 = Bp + (((size_t)(nb0 + 1) * KB16 + 1) * 64 + l) * 8;

#define LOADB(BB)                                    \
  {                                                  \
    BB[0][0] = *(const bf16x8*)p00; p00 += 1024;     \
    BB[0][1] = *(const bf16x8*)p01; p01 += 1024;     \
    BB[1][0] = *(const bf16x8*)p10; p10 += 1024;     \
    BB[1][1] = *(const bf16x8*)p11; p11 += 1024;     \
  }

  // lane-constant swizzled A read offsets: row=l31 (+32-mults), k-gran = ks*2+kb
  const int loff0 = l31 * 64 + (((0 + kb) ^ ((l31 >> 1) & 3)) << 4);
  const int loff1 = l31 * 64 + (((2 + kb) ^ ((l31 >> 1) & 3)) << 4);

  char* As0 = smem;
  char* As1 = smem + 16384;
  char* As2 = smem + 32768;

  f32x16 acc[4][2] = {};
  bf16x8 bbA[2][2], bbB[2][2];

  // Prologue: A(0)[2], B(0)[4], A(1)[2]; vmcnt(2) leaves A(1) in flight.
  stageA(0, As0);
  LOADB(bbA);                 // T=0
  stageA(1, As1);
  VM2();
  BARRIER();

#define STEP(J, BBCUR, BBNXT)                                                   \
  {                                                                             \
    if ((J) < NTT - 1) LOADB(BBNXT);                                            \
    if ((J) < NTT - 2) stageA((J) + 2, As2);                                    \
    bf16x8 af[4][2];                                                            \
    _Pragma("unroll") for (int mt = 0; mt < 4; ++mt) {                          \
      const char* p = As0 + wm * 8192 + mt * 2048;                              \
      af[mt][0] = *(const bf16x8*)(p + loff0);                                  \
      af[mt][1] = *(const bf16x8*)(p + loff1);                                  \
    }                                                                           \
    _Pragma("unroll") for (int mt = 0; mt < 4; ++mt)                            \
      _Pragma("unroll") for (int nt = 0; nt < 2; ++nt) {                        \
        acc[mt][nt] = __builtin_amdgcn_mfma_f32_32x32x16_bf16(                  \
            af[mt][0], BBCUR[nt][0], acc[mt][nt], 0, 0, 0);                     \
        acc[mt][nt] = __builtin_amdgcn_mfma_f32_32x32x16_bf16(                  \
            af[mt][1], BBCUR[nt][1], acc[mt][nt], 0, 0, 0);                     \
      }                                                                         \
    if ((J) < NTT - 2) { VM2(); } else if ((J) == NTT - 2) { VM0(); }           \
    if ((J) < NTT - 1) BARRIER();                                               \
    char* ta_ = As0; As0 = As1; As1 = As2; As2 = ta_;                           \
  }

  for (int j = 0; j < NTT; j += 2) {
    STEP(j, bbA, bbB);
    STEP(j + 1, bbB, bbA);
  }
#undef STEP
#undef LOADB

  // ---- epilogue: row = arow + wm*128 + mt*32 + (e&3)+8*(e>>2)+4*kb ; col = bn*256 + wn*64 + nt*32 + l31
  const int r0g = arow + wm * 128 + kb * 4;
  const int c0g = bn * 256 + wn * 64 + l31;
  if constexpr (MODE == 0) {
    const bool isZ = (bn < 8);
    const float* bias = isZ ? bias0 : bias1;
#pragma unroll
    for (int nt = 0; nt < 2; ++nt) {
      const int colg = c0g + nt * 32;
      const int col = isZ ? colg : (colg - 2048);
      const float bv = bias[col];
#pragma unroll
      for (int mt = 0; mt < 4; ++mt)
#pragma unroll
        for (int e = 0; e < 16; ++e) {
          const int row = r0g + mt * 32 + (e & 3) + 8 * (e >> 2);
          const size_t idx = (size_t)row * HID + col;
          const float v = acc[mt][nt][e] + bv;
          if (isZ) {
            Z[idx] = f2bf(fsigmoid(v));
          } else {
            const float rv = fsigmoid(v);
            RHout[idx] = f2bf(rv * h_prev[idx]);
          }
        }
    }
  } else {
#pragma unroll
    for (int nt = 0; nt < 2; ++nt) {
      const int col = c0g + nt * 32;
      const float bv = bias0[col];
#pragma unroll
      for (int mt = 0; mt < 4; ++mt)
#pragma unroll
        for (int e = 0; e < 16; ++e) {
          const int row = r0g + mt * 32 + (e & 3) + 8 * (e >> 2);
          const size_t idx = (size_t)row * HID + col;
          const float nn = ftanh(acc[mt][nt][e] + bv);
          const float zz = bf2f(Z[idx]);
          const float hp = h_prev[idx];
          out[idx] = (1.0f - zz) * hp + zz * nn;
        }
    }
  }
}

extern "C" void kernel_launch(void* const* d_in, const int* in_sizes, int n_in,
                              void* d_out, int out_size, void* d_ws, size_t ws_size,
                              hipStream_t stream) {
  const float* x  = (const float*)d_in[0];
  const float* h  = (const float*)d_in[1];
  const float* Wz = (const float*)d_in[2];
  const float* bz = (const float*)d_in[3];
  const float* Wr = (const float*)d_in[4];
  const float* br = (const float*)d_in[5];
  const float* Wn = (const float*)d_in[6];
  const float* bn = (const float*)d_in[7];
  float* out = (float*)d_out;

  char* ws = (char*)d_ws;
  u16* A1  = (u16*)(ws);                    // 8192*4096*2 = 67108864
  u16* RH  = (u16*)(ws + 67108864);         // 8192*2048*2 = 33554432
  u16* Bp1 = (u16*)(ws + 100663296);        // 4096*4096*2 = 33554432  (frag-packed [Wz‖Wr])
  u16* Bp2 = (u16*)(ws + 134217728);        // 2048*4096*2 = 16777216  (frag-packed Wn)
  u16* Z   = (u16*)(ws + 150994944);        // 8192*2048*2 = 33554432

  (void)hipFuncSetAttribute(reinterpret_cast<const void*>(&gemmbr_kernel<0>),
                            hipFuncAttributeMaxDynamicSharedMemorySize, 49152);
  (void)hipFuncSetAttribute(reinterpret_cast<const void*>(&gemmbr_kernel<1>),
                            hipFuncAttributeMaxDynamicSharedMemorySize, 49152);

  pack_A_kernel<<<16384, 256, 0, stream>>>(x, h, A1);
  dim3 tb(32, 8);
  packW_kernel<<<dim3(64, 128), tb, 0, stream>>>(Wz, Bp1);
  packW_kernel<<<dim3(64, 128), tb, 0, stream>>>(Wr, Bp1 + (size_t)2048 * 4096);
  packW_kernel<<<dim3(64, 128), tb, 0, stream>>>(Wn, Bp2);

  gemmbr_kernel<0><<<dim3(512), 512, 49152, stream>>>(A1, nullptr, Bp1, h, bz, br, Z, RH, nullptr);
  gemmbr_kernel<1><<<dim3(256), 512, 49152, stream>>>(A1, RH, Bp2, h, bn, nullptr, Z, nullptr, out);
}

// Round 10
// 593.674 us; speedup vs baseline: 2.8316x; 1.2375x over previous
//
#include <hip/hip_runtime.h>
#include <hip/hip_bf16.h>
#include <stdint.h>

typedef unsigned short u16;
typedef __attribute__((ext_vector_type(8))) __bf16 bf16x8;
typedef __attribute__((ext_vector_type(4))) float f32x4;

#define BATCH 8192
#define HID   2048
#define COMB  4096
#define NT    64   // K tiles of 64

__device__ __forceinline__ u16 f2bf(float f) {
  uint32_t u = __float_as_uint(f);
  u += 0x7fffu + ((u >> 16) & 1u);
  return (u16)(u >> 16);
}
__device__ __forceinline__ float bf2f(u16 b) {
  return __uint_as_float(((uint32_t)b) << 16);
}
__device__ __forceinline__ float fsigmoid(float x) { return 1.0f / (1.0f + __expf(-x)); }
__device__ __forceinline__ float ftanh(float x) { return 1.0f - 2.0f / (__expf(2.0f * x) + 1.0f); }

__device__ __forceinline__ void gload_lds16(const void* g, void* l) {
  __builtin_amdgcn_global_load_lds(
      (__attribute__((address_space(1))) void*)(uintptr_t)g,
      (__attribute__((address_space(3))) void*)(uintptr_t)l,
      16, 0, 0);
}

#define BARRIER() do { asm volatile("" ::: "memory"); __builtin_amdgcn_s_barrier(); asm volatile("" ::: "memory"); } while (0)
#define LGKM0()   asm volatile("s_waitcnt lgkmcnt(0)" ::: "memory")
#define LGKM8()   asm volatile("s_waitcnt lgkmcnt(8)" ::: "memory")
#define VM6()     asm volatile("s_waitcnt vmcnt(6)" ::: "memory")
#define VM0()     asm volatile("s_waitcnt vmcnt(0)" ::: "memory")

// Stage one 128x64 bf16 half-tile (2 gloads/wave): linear LDS dest,
// inverse-XOR-swizzled global src. LDS(row, g16) = global(row, g16 ^ (row&7)).
__device__ __forceinline__ void stage_half(const u16* __restrict__ src, size_t ld,
                                           char* ldsHalf, int w, int l) {
  const int lrow = l >> 3;
  const int g    = (l & 7) ^ (lrow & 7);
#pragma unroll
  for (int i = 0; i < 2; ++i) {
    const int r0 = (w * 2 + i) * 8;
    gload_lds16(src + (size_t)(r0 + lrow) * ld + g * 8, ldsHalf + r0 * 128);
  }
}

// Stage one 64-row quarter of a 128-row half slot (1 gload/wave). q in {0,1}.
__device__ __forceinline__ void stage_q(const u16* __restrict__ src, size_t ld,
                                        char* ldsHalf, int q, int w, int l) {
  const int lrow = l >> 3;
  const int g    = (l & 7) ^ (lrow & 7);
  const int r0   = q * 64 + w * 8;
  gload_lds16(src + (size_t)(r0 + lrow) * ld + g * 8, ldsHalf + r0 * 128);
}

// ks OUTERMOST: consecutive MFMAs write different accumulators (no back-to-back
// same-acc dependency; reuse distance 8 instrs > MFMA latency).
#define MFMA_QUAD(MH, NH)                                                          \
  {                                                                                \
    _Pragma("unroll") for (int ks_ = 0; ks_ < 2; ++ks_) {                          \
      _Pragma("unroll") for (int m_ = 0; m_ < 4; ++m_) {                           \
        _Pragma("unroll") for (int n_ = 0; n_ < 2; ++n_) {                         \
          acc[(MH)*4 + m_][(NH)*2 + n_] = __builtin_amdgcn_mfma_f32_16x16x32_bf16( \
              af[(MH)*4 + m_][ks_], bb[(NH)*2 + n_][ks_],                          \
              acc[(MH)*4 + m_][(NH)*2 + n_], 0, 0, 0);                             \
        } } }                                                                      \
  }

// ---- pack [x | h_prev] f32 -> A1 bf16 [8192][4096] ----
__global__ void pack_A_kernel(const float* __restrict__ x, const float* __restrict__ h,
                              u16* __restrict__ A1) {
  const size_t tid = (size_t)blockIdx.x * blockDim.x + threadIdx.x;
  const int r  = (int)(tid >> 9);
  const int c8 = (int)(tid & 511);
  const float* s = (c8 < 256) ? (x + (size_t)r * 2048 + (size_t)c8 * 8)
                              : (h + (size_t)r * 2048 + (size_t)(c8 - 256) * 8);
  const float4 v0 = ((const float4*)s)[0];
  const float4 v1 = ((const float4*)s)[1];
  const uint32_t p0 = (uint32_t)f2bf(v0.x) | ((uint32_t)f2bf(v0.y) << 16);
  const uint32_t p1 = (uint32_t)f2bf(v0.z) | ((uint32_t)f2bf(v0.w) << 16);
  const uint32_t p2 = (uint32_t)f2bf(v1.x) | ((uint32_t)f2bf(v1.y) << 16);
  const uint32_t p3 = (uint32_t)f2bf(v1.z) | ((uint32_t)f2bf(v1.w) << 16);
  *(uint4*)(A1 + tid * 8) = make_uint4(p0, p1, p2, p3);
}

// ---- transpose W [4096][2048] f32 -> dst [2048][4096] bf16 ----
__global__ void transpose_w_kernel(const float* __restrict__ src, u16* __restrict__ dst) {
  __shared__ float tile[32][33];
  const int n0 = blockIdx.x * 32;
  const int k0 = blockIdx.y * 32;
  const int tx = threadIdx.x, ty = threadIdx.y;
#pragma unroll
  for (int i = 0; i < 32; i += 8)
    tile[ty + i][tx] = src[(size_t)(k0 + ty + i) * 2048 + n0 + tx];
  __syncthreads();
#pragma unroll
  for (int i = 0; i < 32; i += 8)
    dst[(size_t)(n0 + ty + i) * 4096 + k0 + tx] = f2bf(tile[tx][ty + i]);
}

// ---- 256x256x64 8-phase GEMM, reads spread 12/8/4/0. MODE 0: z|r; MODE 1: n ----
template <int MODE>
__global__ __launch_bounds__(512, 2) void gemm8p_kernel(
    const u16* __restrict__ A1, const u16* __restrict__ RH,
    const u16* __restrict__ Bt, const float* __restrict__ h_prev,
    const float* __restrict__ bias0, const float* __restrict__ bias1,
    u16* __restrict__ Z, u16* __restrict__ RHout, float* __restrict__ out) {
  extern __shared__ char smem[];   // [0,64K): A slots (parity*2+half)<<14 ; [64K,128K): B slots
  constexpr int NBN = (MODE == 0) ? 16 : 8;

  const int t = threadIdx.x;
  const int l = t & 63, w = t >> 6;
  const int wm = w >> 2, wn = w & 3;
  const int lr = l & 15, khi = l >> 4;

  const int nwg = 32 * NBN;
  int bid = blockIdx.x;
  bid = (bid & 7) * (nwg >> 3) + (bid >> 3);
  const int bm = bid / NBN, bn = bid % NBN;
  const int arow = bm * 256;
  const int brow = bn * 256;

  char* Abase = smem;
  char* Bbase = smem + 65536;

  auto asrc = [&](int T, int half) -> const u16* {
    if constexpr (MODE == 1) {
      if (T >= 32) return RH + (size_t)(arow + half * 128) * HID + (T * 64 - 2048);
    }
    return A1 + (size_t)(arow + half * 128) * COMB + T * 64;
  };
  auto ald = [&](int T) -> size_t {
    if constexpr (MODE == 1) { if (T >= 32) return HID; }
    return COMB;
  };
  auto stageAq = [&](int T, int half, int q) {
    stage_q(asrc(T, half), ald(T), Abase + (((T & 1) * 2 + half) << 14), q, w, l);
  };
  auto stageB = [&](int T, int half) {
    stage_half(Bt + (size_t)(brow + half * 128) * COMB + T * 64, COMB,
               Bbase + (((T & 1) * 2 + half) << 14), w, l);
  };

  // Lane-constant swizzled read offsets (row&7 == lr&7 for all fragment rows).
  const int loff0 = lr * 128 + ((khi       ^ (lr & 7)) << 4);
  const int loff1 = lr * 128 + (((4 + khi) ^ (lr & 7)) << 4);

  // Prologue: tile0 {A q0,q1 both halves; B0; B1} + tile1 {A all quarters; B0}.
  stageAq(0, 0, 0); stageAq(0, 1, 0); stageAq(0, 0, 1); stageAq(0, 1, 1);
  stageB(0, 0); stageB(0, 1);
  stageAq(1, 0, 0); stageAq(1, 1, 0); stageAq(1, 0, 1); stageAq(1, 1, 1);
  stageB(1, 0);
  VM6();          // drain tile 0 (8 loads); leave {A(1) x4, B0(1) x2}
  BARRIER();

  f32x4 acc[8][4] = {};
  bf16x8 af[8][2], bb[4][2];

#pragma unroll 2
  for (int j = 0; j < NT; ++j) {
    const int p = j & 1;
    const char* Ah = Abase + (((p << 1) + wm) << 14);
    const char* Bh = Bbase + (((p << 1) + (wn >> 1)) << 14) + (wn & 1) * 64 * 128;

    // ---- ph0: read afLo(8) + bbLo(4); stage B1(j+1); lgkm8; Q(0,0)
#pragma unroll
    for (int m = 0; m < 4; ++m) {
      af[m][0] = *(const bf16x8*)(Ah + m * 2048 + loff0);
      af[m][1] = *(const bf16x8*)(Ah + m * 2048 + loff1);
    }
#pragma unroll
    for (int n = 0; n < 2; ++n) {
      bb[n][0] = *(const bf16x8*)(Bh + n * 2048 + loff0);
      bb[n][1] = *(const bf16x8*)(Bh + n * 2048 + loff1);
    }
    if (j < NT - 1) stageB(j + 1, 1);
    LGKM8();
    BARRIER();
    LGKM0();
    __builtin_amdgcn_s_setprio(1);
    MFMA_QUAD(0, 0);
    __builtin_amdgcn_s_setprio(0);
    BARRIER();

    // ---- ph1: read afHi(8); stage A(j+2) quarter0 of both halves; Q(1,0)
#pragma unroll
    for (int m = 4; m < 8; ++m) {
      af[m][0] = *(const bf16x8*)(Ah + m * 2048 + loff0);
      af[m][1] = *(const bf16x8*)(Ah + m * 2048 + loff1);
    }
    if (j < NT - 2) { stageAq(j + 2, 0, 0); stageAq(j + 2, 1, 0); }
    BARRIER();
    LGKM0();
    __builtin_amdgcn_s_setprio(1);
    MFMA_QUAD(1, 0);
    __builtin_amdgcn_s_setprio(0);
    BARRIER();

    // ---- ph2: read bbHi(4); stage A(j+2) quarter1 of both halves; Q(1,1)
#pragma unroll
    for (int n = 2; n < 4; ++n) {
      bb[n][0] = *(const bf16x8*)(Bh + n * 2048 + loff0);
      bb[n][1] = *(const bf16x8*)(Bh + n * 2048 + loff1);
    }
    if (j < NT - 2) { stageAq(j + 2, 0, 1); stageAq(j + 2, 1, 1); }
    BARRIER();
    LGKM0();
    __builtin_amdgcn_s_setprio(1);
    MFMA_QUAD(1, 1);
    __builtin_amdgcn_s_setprio(0);
    BARRIER();

    // ---- ph3: stage B0(j+2); Q(0,1); counted vmcnt at tile boundary
    if (j < NT - 2) stageB(j + 2, 0);
    BARRIER();
    __builtin_amdgcn_s_setprio(1);
    MFMA_QUAD(0, 1);
    __builtin_amdgcn_s_setprio(0);
    if (j < NT - 2) { VM6(); } else { VM0(); }
    BARRIER();
  }

  // ---- epilogue
  const int r0g = arow + wm * 128 + khi * 4;
  const int c0g = brow + wn * 64 + lr;
  if constexpr (MODE == 0) {
    const bool isZ = (bn < 8);
    const float* bias = isZ ? bias0 : bias1;
#pragma unroll
    for (int n = 0; n < 4; ++n) {
      const int colg = c0g + n * 16;
      const int col = isZ ? colg : (colg - 2048);
      const float bv = bias[col];
#pragma unroll
      for (int m = 0; m < 8; ++m)
#pragma unroll
        for (int r = 0; r < 4; ++r) {
          const int row = r0g + m * 16 + r;
          const size_t idx = (size_t)row * HID + col;
          const float v = acc[m][n][r] + bv;
          if (isZ) {
            Z[idx] = f2bf(fsigmoid(v));
          } else {
            const float rv = fsigmoid(v);
            RHout[idx] = f2bf(rv * h_prev[idx]);
          }
        }
    }
  } else {
#pragma unroll
    for (int n = 0; n < 4; ++n) {
      const int col = c0g + n * 16;
      const float bv = bias0[col];
#pragma unroll
      for (int m = 0; m < 8; ++m)
#pragma unroll
        for (int r = 0; r < 4; ++r) {
          const int row = r0g + m * 16 + r;
          const size_t idx = (size_t)row * HID + col;
          const float nn = ftanh(acc[m][n][r] + bv);
          const float zz = bf2f(Z[idx]);
          const float hp = h_prev[idx];
          out[idx] = (1.0f - zz) * hp + zz * nn;
        }
    }
  }
}

extern "C" void kernel_launch(void* const* d_in, const int* in_sizes, int n_in,
                              void* d_out, int out_size, void* d_ws, size_t ws_size,
                              hipStream_t stream) {
  const float* x  = (const float*)d_in[0];
  const float* h  = (const float*)d_in[1];
  const float* Wz = (const float*)d_in[2];
  const float* bz = (const float*)d_in[3];
  const float* Wr = (const float*)d_in[4];
  const float* br = (const float*)d_in[5];
  const float* Wn = (const float*)d_in[6];
  const float* bn = (const float*)d_in[7];
  float* out = (float*)d_out;

  char* ws = (char*)d_ws;
  u16* A1  = (u16*)(ws);                    // 8192*4096*2 = 67108864
  u16* RH  = (u16*)(ws + 67108864);         // 8192*2048*2 = 33554432
  u16* B1t = (u16*)(ws + 100663296);        // 4096*4096*2 = 33554432  ([Wz;Wr]^T)
  u16* B2t = (u16*)(ws + 134217728);        // 2048*4096*2 = 16777216  (Wn^T)
  u16* Z   = (u16*)(ws + 150994944);        // 8192*2048*2 = 33554432

  (void)hipFuncSetAttribute(reinterpret_cast<const void*>(&gemm8p_kernel<0>),
                            hipFuncAttributeMaxDynamicSharedMemorySize, 131072);
  (void)hipFuncSetAttribute(reinterpret_cast<const void*>(&gemm8p_kernel<1>),
                            hipFuncAttributeMaxDynamicSharedMemorySize, 131072);

  pack_A_kernel<<<16384, 256, 0, stream>>>(x, h, A1);
  dim3 tb(32, 8);
  transpose_w_kernel<<<dim3(64, 128), tb, 0, stream>>>(Wz, B1t);
  transpose_w_kernel<<<dim3(64, 128), tb, 0, stream>>>(Wr, B1t + (size_t)2048 * 4096);
  transpose_w_kernel<<<dim3(64, 128), tb, 0, stream>>>(Wn, B2t);

  gemm8p_kernel<0><<<dim3(512), 512, 131072, stream>>>(A1, nullptr, B1t, h, bz, br, Z, RH, nullptr);
  gemm8p_kernel<1><<<dim3(256), 512, 131072, stream>>>(A1, RH, B2t, h, bn, nullptr, Z, nullptr, out);
}

// Round 11
// 592.426 us; speedup vs baseline: 2.8375x; 1.0021x over previous
//
#include <hip/hip_runtime.h>
#include <hip/hip_bf16.h>
#include <stdint.h>

typedef unsigned short u16;
typedef __attribute__((ext_vector_type(8))) __bf16 bf16x8;
typedef __attribute__((ext_vector_type(4))) float f32x4;

#define BATCH 8192
#define HID   2048
#define COMB  4096
#define NT    64   // K tiles of 64

__device__ __forceinline__ u16 f2bf(float f) {
  uint32_t u = __float_as_uint(f);
  u += 0x7fffu + ((u >> 16) & 1u);
  return (u16)(u >> 16);
}
__device__ __forceinline__ float bf2f(u16 b) {
  return __uint_as_float(((uint32_t)b) << 16);
}
__device__ __forceinline__ float fsigmoid(float x) { return 1.0f / (1.0f + __expf(-x)); }
__device__ __forceinline__ float ftanh(float x) { return 1.0f - 2.0f / (__expf(2.0f * x) + 1.0f); }

__device__ __forceinline__ void gload_lds16(const void* g, void* l) {
  __builtin_amdgcn_global_load_lds(
      (__attribute__((address_space(1))) void*)(uintptr_t)g,
      (__attribute__((address_space(3))) void*)(uintptr_t)l,
      16, 0, 0);
}

// Plain barrier: NOT a compiler memory fence -> scheduler may overlap ds_reads
// of the next phase under this phase's MFMAs (m201 template behavior).
#define BAR() __builtin_amdgcn_s_barrier()
// Tile-boundary waits KEEP the memory clobber: they certify cross-wave LDS slot
// reuse; the clobber blocks ds_read hoisting across the tile boundary.
#define VM6() asm volatile("s_waitcnt vmcnt(6)" ::: "memory")
#define VM0() asm volatile("s_waitcnt vmcnt(0)" ::: "memory")

// Stage one 128x64 bf16 half-tile (2 gloads/wave): linear LDS dest,
// inverse-XOR-swizzled global src. LDS(row, g16) = global(row, g16 ^ (row&7)).
__device__ __forceinline__ void stage_half(const u16* __restrict__ src, size_t ld,
                                           char* ldsHalf, int w, int l) {
  const int lrow = l >> 3;
  const int g    = (l & 7) ^ (lrow & 7);
#pragma unroll
  for (int i = 0; i < 2; ++i) {
    const int r0 = (w * 2 + i) * 8;
    gload_lds16(src + (size_t)(r0 + lrow) * ld + g * 8, ldsHalf + r0 * 128);
  }
}

// Stage one 64-row quarter of a 128-row half slot (1 gload/wave). q in {0,1}.
__device__ __forceinline__ void stage_q(const u16* __restrict__ src, size_t ld,
                                        char* ldsHalf, int q, int w, int l) {
  const int lrow = l >> 3;
  const int g    = (l & 7) ^ (lrow & 7);
  const int r0   = q * 64 + w * 8;
  gload_lds16(src + (size_t)(r0 + lrow) * ld + g * 8, ldsHalf + r0 * 128);
}

#define MFMA_QUAD(MH, NH)                                                          \
  {                                                                                \
    _Pragma("unroll") for (int ks_ = 0; ks_ < 2; ++ks_) {                          \
      _Pragma("unroll") for (int m_ = 0; m_ < 4; ++m_) {                           \
        _Pragma("unroll") for (int n_ = 0; n_ < 2; ++n_) {                         \
          acc[(MH)*4 + m_][(NH)*2 + n_] = __builtin_amdgcn_mfma_f32_16x16x32_bf16( \
              af[(MH)*4 + m_][ks_], bb[(NH)*2 + n_][ks_],                          \
              acc[(MH)*4 + m_][(NH)*2 + n_], 0, 0, 0);                             \
        } } }                                                                      \
  }

// ---- pack [x | h_prev] f32 -> A1 bf16 [8192][4096] ----
__global__ void pack_A_kernel(const float* __restrict__ x, const float* __restrict__ h,
                              u16* __restrict__ A1) {
  const size_t tid = (size_t)blockIdx.x * blockDim.x + threadIdx.x;
  const int r  = (int)(tid >> 9);
  const int c8 = (int)(tid & 511);
  const float* s = (c8 < 256) ? (x + (size_t)r * 2048 + (size_t)c8 * 8)
                              : (h + (size_t)r * 2048 + (size_t)(c8 - 256) * 8);
  const float4 v0 = ((const float4*)s)[0];
  const float4 v1 = ((const float4*)s)[1];
  const uint32_t p0 = (uint32_t)f2bf(v0.x) | ((uint32_t)f2bf(v0.y) << 16);
  const uint32_t p1 = (uint32_t)f2bf(v0.z) | ((uint32_t)f2bf(v0.w) << 16);
  const uint32_t p2 = (uint32_t)f2bf(v1.x) | ((uint32_t)f2bf(v1.y) << 16);
  const uint32_t p3 = (uint32_t)f2bf(v1.z) | ((uint32_t)f2bf(v1.w) << 16);
  *(uint4*)(A1 + tid * 8) = make_uint4(p0, p1, p2, p3);
}

// ---- transpose W [4096][2048] f32 -> dst [2048][4096] bf16 ----
__global__ void transpose_w_kernel(const float* __restrict__ src, u16* __restrict__ dst) {
  __shared__ float tile[32][33];
  const int n0 = blockIdx.x * 32;
  const int k0 = blockIdx.y * 32;
  const int tx = threadIdx.x, ty = threadIdx.y;
#pragma unroll
  for (int i = 0; i < 32; i += 8)
    tile[ty + i][tx] = src[(size_t)(k0 + ty + i) * 2048 + n0 + tx];
  __syncthreads();
#pragma unroll
  for (int i = 0; i < 32; i += 8)
    dst[(size_t)(n0 + ty + i) * 4096 + k0 + tx] = f2bf(tile[tx][ty + i]);
}

// ---- 256x256x64 8-phase GEMM, relaxed phase fences. MODE 0: z|r; MODE 1: n ----
template <int MODE>
__global__ __launch_bounds__(512, 2) void gemm8p_kernel(
    const u16* __restrict__ A1, const u16* __restrict__ RH,
    const u16* __restrict__ Bt, const float* __restrict__ h_prev,
    const float* __restrict__ bias0, const float* __restrict__ bias1,
    u16* __restrict__ Z, u16* __restrict__ RHout, float* __restrict__ out) {
  extern __shared__ char smem[];   // [0,64K): A slots (parity*2+half)<<14 ; [64K,128K): B slots
  constexpr int NBN = (MODE == 0) ? 16 : 8;

  const int t = threadIdx.x;
  const int l = t & 63, w = t >> 6;
  const int wm = w >> 2, wn = w & 3;
  const int lr = l & 15, khi = l >> 4;

  const int nwg = 32 * NBN;
  int bid = blockIdx.x;
  bid = (bid & 7) * (nwg >> 3) + (bid >> 3);
  const int bm = bid / NBN, bn = bid % NBN;
  const int arow = bm * 256;
  const int brow = bn * 256;

  char* Abase = smem;
  char* Bbase = smem + 65536;

  auto asrc = [&](int T, int half) -> const u16* {
    if constexpr (MODE == 1) {
      if (T >= 32) return RH + (size_t)(arow + half * 128) * HID + (T * 64 - 2048);
    }
    return A1 + (size_t)(arow + half * 128) * COMB + T * 64;
  };
  auto ald = [&](int T) -> size_t {
    if constexpr (MODE == 1) { if (T >= 32) return HID; }
    return COMB;
  };
  auto stageAq = [&](int T, int half, int q) {
    stage_q(asrc(T, half), ald(T), Abase + (((T & 1) * 2 + half) << 14), q, w, l);
  };
  auto stageB = [&](int T, int half) {
    stage_half(Bt + (size_t)(brow + half * 128) * COMB + T * 64, COMB,
               Bbase + (((T & 1) * 2 + half) << 14), w, l);
  };

  // Lane-constant swizzled read offsets (row&7 == lr&7 for all fragment rows).
  const int loff0 = lr * 128 + ((khi       ^ (lr & 7)) << 4);
  const int loff1 = lr * 128 + (((4 + khi) ^ (lr & 7)) << 4);

  // Prologue: tile0 {A q0,q1 both halves; B0; B1} + tile1 {A all quarters; B0}.
  stageAq(0, 0, 0); stageAq(0, 1, 0); stageAq(0, 0, 1); stageAq(0, 1, 1);
  stageB(0, 0); stageB(0, 1);
  stageAq(1, 0, 0); stageAq(1, 1, 0); stageAq(1, 0, 1); stageAq(1, 1, 1);
  stageB(1, 0);
  VM6();          // drain tile 0 (8 loads); leave {A(1) x4, B0(1) x2}
  BAR();

  f32x4 acc[8][4] = {};
  bf16x8 af[8][2], bb[4][2];

#pragma unroll 2
  for (int j = 0; j < NT; ++j) {
    const int p = j & 1;
    const char* Ah = Abase + (((p << 1) + wm) << 14);
    const char* Bh = Bbase + (((p << 1) + (wn >> 1)) << 14) + (wn & 1) * 64 * 128;

    // ---- ph0: read afLo(8) + bbLo(4); stage B1(j+1); Q(0,0)
#pragma unroll
    for (int m = 0; m < 4; ++m) {
      af[m][0] = *(const bf16x8*)(Ah + m * 2048 + loff0);
      af[m][1] = *(const bf16x8*)(Ah + m * 2048 + loff1);
    }
#pragma unroll
    for (int n = 0; n < 2; ++n) {
      bb[n][0] = *(const bf16x8*)(Bh + n * 2048 + loff0);
      bb[n][1] = *(const bf16x8*)(Bh + n * 2048 + loff1);
    }
    if (j < NT - 1) stageB(j + 1, 1);
    BAR();
    __builtin_amdgcn_s_setprio(1);
    MFMA_QUAD(0, 0);
    __builtin_amdgcn_s_setprio(0);
    BAR();

    // ---- ph1: read afHi(8); stage A(j+2) quarter0 of both halves; Q(1,0)
#pragma unroll
    for (int m = 4; m < 8; ++m) {
      af[m][0] = *(const bf16x8*)(Ah + m * 2048 + loff0);
      af[m][1] = *(const bf16x8*)(Ah + m * 2048 + loff1);
    }
    if (j < NT - 2) { stageAq(j + 2, 0, 0); stageAq(j + 2, 1, 0); }
    BAR();
    __builtin_amdgcn_s_setprio(1);
    MFMA_QUAD(1, 0);
    __builtin_amdgcn_s_setprio(0);
    BAR();

    // ---- ph2: read bbHi(4); stage A(j+2) quarter1 of both halves; Q(1,1)
#pragma unroll
    for (int n = 2; n < 4; ++n) {
      bb[n][0] = *(const bf16x8*)(Bh + n * 2048 + loff0);
      bb[n][1] = *(const bf16x8*)(Bh + n * 2048 + loff1);
    }
    if (j < NT - 2) { stageAq(j + 2, 0, 1); stageAq(j + 2, 1, 1); }
    BAR();
    __builtin_amdgcn_s_setprio(1);
    MFMA_QUAD(1, 1);
    __builtin_amdgcn_s_setprio(0);
    BAR();

    // ---- ph3: stage B0(j+2); Q(0,1); counted vmcnt at tile boundary
    if (j < NT - 2) stageB(j + 2, 0);
    BAR();
    __builtin_amdgcn_s_setprio(1);
    MFMA_QUAD(0, 1);
    __builtin_amdgcn_s_setprio(0);
    if (j < NT - 2) { VM6(); } else { VM0(); }
    BAR();
  }

  // ---- epilogue
  const int r0g = arow + wm * 128 + khi * 4;
  const int c0g = brow + wn * 64 + lr;
  if constexpr (MODE == 0) {
    const bool isZ = (bn < 8);
    const float* bias = isZ ? bias0 : bias1;
#pragma unroll
    for (int n = 0; n < 4; ++n) {
      const int colg = c0g + n * 16;
      const int col = isZ ? colg : (colg - 2048);
      const float bv = bias[col];
#pragma unroll
      for (int m = 0; m < 8; ++m)
#pragma unroll
        for (int r = 0; r < 4; ++r) {
          const int row = r0g + m * 16 + r;
          const size_t idx = (size_t)row * HID + col;
          const float v = acc[m][n][r] + bv;
          if (isZ) {
            Z[idx] = f2bf(fsigmoid(v));
          } else {
            const float rv = fsigmoid(v);
            RHout[idx] = f2bf(rv * h_prev[idx]);
          }
        }
    }
  } else {
#pragma unroll
    for (int n = 0; n < 4; ++n) {
      const int col = c0g + n * 16;
      const float bv = bias0[col];
#pragma unroll
      for (int m = 0; m < 8; ++m)
#pragma unroll
        for (int r = 0; r < 4; ++r) {
          const int row = r0g + m * 16 + r;
          const size_t idx = (size_t)row * HID + col;
          const float nn = ftanh(acc[m][n][r] + bv);
          const float zz = bf2f(Z[idx]);
          const float hp = h_prev[idx];
          out[idx] = (1.0f - zz) * hp + zz * nn;
        }
    }
  }
}

extern "C" void kernel_launch(void* const* d_in, const int* in_sizes, int n_in,
                              void* d_out, int out_size, void* d_ws, size_t ws_size,
                              hipStream_t stream) {
  const float* x  = (const float*)d_in[0];
  const float* h  = (const float*)d_in[1];
  const float* Wz = (const float*)d_in[2];
  const float* bz = (const float*)d_in[3];
  const float* Wr = (const float*)d_in[4];
  const float* br = (const float*)d_in[5];
  const float* Wn = (const float*)d_in[6];
  const float* bn = (const float*)d_in[7];
  float* out = (float*)d_out;

  char* ws = (char*)d_ws;
  u16* A1  = (u16*)(ws);                    // 8192*4096*2 = 67108864
  u16* RH  = (u16*)(ws + 67108864);         // 8192*2048*2 = 33554432
  u16* B1t = (u16*)(ws + 100663296);        // 4096*4096*2 = 33554432  ([Wz;Wr]^T)
  u16* B2t = (u16*)(ws + 134217728);        // 2048*4096*2 = 16777216  (Wn^T)
  u16* Z   = (u16*)(ws + 150994944);        // 8192*2048*2 = 33554432

  (void)hipFuncSetAttribute(reinterpret_cast<const void*>(&gemm8p_kernel<0>),
                            hipFuncAttributeMaxDynamicSharedMemorySize, 131072);
  (void)hipFuncSetAttribute(reinterpret_cast<const void*>(&gemm8p_kernel<1>),
                            hipFuncAttributeMaxDynamicSharedMemorySize, 131072);

  pack_A_kernel<<<16384, 256, 0, stream>>>(x, h, A1);
  dim3 tb(32, 8);
  transpose_w_kernel<<<dim3(64, 128), tb, 0, stream>>>(Wz, B1t);
  transpose_w_kernel<<<dim3(64, 128), tb, 0, stream>>>(Wr, B1t + (size_t)2048 * 4096);
  transpose_w_kernel<<<dim3(64, 128), tb, 0, stream>>>(Wn, B2t);

  gemm8p_kernel<0><<<dim3(512), 512, 131072, stream>>>(A1, nullptr, B1t, h, bz, br, Z, RH, nullptr);
  gemm8p_kernel<1><<<dim3(256), 512, 131072, stream>>>(A1, RH, B2t, h, bn, nullptr, Z, nullptr, out);
}